// Round 8
// baseline (308.098 us; speedup 1.0000x reference)
//
#include <hip/hip_runtime.h>

#define SLOPE 0.22916666666666666f  // (1/8 + 1/3) / 2
#define ALONE_CAP 2048              // expected alone nodes ~2.3

typedef __attribute__((ext_vector_type(8))) short bfrag;   // 8 x bf16 bits
typedef __attribute__((ext_vector_type(4))) float ffrag;   // 4 x f32 acc

__device__ __forceinline__ unsigned short rne16(float f) {
    unsigned u = __float_as_uint(f);
    return (unsigned short)((u + 0x7FFFu + ((u >> 16) & 1u)) >> 16);
}
__device__ __forceinline__ float bf2f(unsigned short h) {
    return __uint_as_float(((unsigned)h) << 16);
}
// interleaved split word: hi bf16 in [31:16], lo bf16 in [15:0]
__device__ __forceinline__ unsigned packsplit(float f) {
    unsigned short hi = rne16(f);
    unsigned short lo = rne16(f - bf2f(hi));
    return ((unsigned)hi << 16) | lo;
}
__device__ __forceinline__ float recon(unsigned u) {
    return __uint_as_float(u & 0xFFFF0000u) + __uint_as_float(u << 16);
}
__device__ __forceinline__ float4 recon4(uint4 u) {
    return make_float4(recon(u.x), recon(u.y), recon(u.z), recon(u.w));
}

// ---------------------------------------------------------------- prep
// Fused: [0,eb) count in-degrees; [eb,eb+cb) split ent -> interleaved Esp;
// [eb+cb, +32) pack W into MFMA B-fragment order (hi/lo planes).
__global__ __launch_bounds__(256) void prep_kernel(
    const int* __restrict__ dst, int* __restrict__ deg, int e, int eb,
    const float* __restrict__ ent, unsigned* __restrict__ Esp,
    int total4, int cb,
    const float* __restrict__ Wn, const float* __restrict__ Wl,
    ushort* __restrict__ packW) {
    int b = blockIdx.x;
    if (b < eb) {
        int i = b * 256 + threadIdx.x;
        if (i < e) atomicAdd(&deg[dst[i]], 1);
    } else if (b < eb + cb) {
        int i = (b - eb) * 256 + threadIdx.x;
        if (i >= total4) return;
        float4 v = ((const float4*)ent)[i];
        uint4 w;
        w.x = packsplit(v.x); w.y = packsplit(v.y);
        w.z = packsplit(v.z); w.w = packsplit(v.w);
        ((uint4*)Esp)[i] = w;
    } else {
        // packed[((kc*128 + n)*4 + quad)*8 + j] = bf16(W[kc*32 + quad*8 + j][n])
        int t = (b - eb - cb) * 256 + threadIdx.x;
        if (t >= 4 * 4 * 128 * 4) return;
        int quad = t & 3;
        int nn   = (t >> 2) & 127;
        int kc   = (t >> 9) & 3;
        int mat  = t >> 11;   // 0=Wn L0, 1=Wl L0, 2=Wn L1, 3=Wl L1
        const float* W = ((mat & 1) ? Wl : Wn) + (mat >> 1) * 16384;
        ushort* oh = packW + mat * 32768;
        ushort* ol = oh + 16384;
        int obase = ((kc * 128 + nn) * 4 + quad) * 8;
        #pragma unroll
        for (int j = 0; j < 8; ++j) {
            float w = W[(kc * 32 + quad * 8 + j) * 128 + nn];
            unsigned short hi = rne16(w);
            oh[obase + j] = hi;
            ol[obase + j] = rne16(w - bf2f(hi));
        }
    }
}

// --- single-kernel exclusive scan + alone detection -----------------------
// Each block sums its 1024-chunk, publishes (partial, flag) with agent-scope
// release, then polls all predecessor flags (grid = nparts <= 64 blocks, all
// co-resident on 256 CUs -> no deadlock). flags/partials pre-zeroed.
__global__ __launch_bounds__(256) void scan_kernel(const int* __restrict__ deg,
                                                   int* __restrict__ partial,
                                                   int* __restrict__ flag,
                                                   int* __restrict__ row_off,
                                                   int* __restrict__ alone_list,
                                                   int* __restrict__ alone_count, int n) {
    __shared__ int wsum[4];
    __shared__ int sbase;
    int bid = blockIdx.x;
    int t = threadIdx.x, lane = t & 63, wid = t >> 6;
    int base = bid * 1024;
    int i0 = base + t * 4;
    int v0 = (i0 + 0 < n) ? deg[i0 + 0] : 0;
    int v1 = (i0 + 1 < n) ? deg[i0 + 1] : 0;
    int v2 = (i0 + 2 < n) ? deg[i0 + 2] : 0;
    int v3 = (i0 + 3 < n) ? deg[i0 + 3] : 0;
    int s = v0 + v1 + v2 + v3;
    int x = s;
    #pragma unroll
    for (int off = 1; off < 64; off <<= 1) {
        int y = __shfl_up(x, off, 64);
        if (lane >= off) x += y;
    }
    if (lane == 63) wsum[wid] = x;
    __syncthreads();
    // publish this block's total
    if (t == 0) {
        int total = wsum[0] + wsum[1] + wsum[2] + wsum[3];
        __hip_atomic_store(&partial[bid], total, __ATOMIC_RELEASE, __HIP_MEMORY_SCOPE_AGENT);
        __hip_atomic_store(&flag[bid], 1, __ATOMIC_RELEASE, __HIP_MEMORY_SCOPE_AGENT);
    }
    // wave 0: gather predecessors' partials (poll)
    if (wid == 0) {
        int v = 0;
        if (lane < bid) {
            while (__hip_atomic_load(&flag[lane], __ATOMIC_ACQUIRE, __HIP_MEMORY_SCOPE_AGENT) == 0) {}
            v = __hip_atomic_load(&partial[lane], __ATOMIC_ACQUIRE, __HIP_MEMORY_SCOPE_AGENT);
        }
        #pragma unroll
        for (int off = 1; off < 64; off <<= 1) v += __shfl_xor(v, off, 64);
        if (lane == 0) sbase = v;
    }
    __syncthreads();
    int wbase = 0;
    #pragma unroll
    for (int w = 0; w < 4; ++w) { int ws = wsum[w]; if (w < wid) wbase += ws; }
    int p = sbase + wbase + x - s;
    if (i0 + 0 <= n) row_off[i0 + 0] = p;
    p += v0;
    if (i0 + 1 <= n) row_off[i0 + 1] = p;
    p += v1;
    if (i0 + 2 <= n) row_off[i0 + 2] = p;
    p += v2;
    if (i0 + 3 <= n) row_off[i0 + 3] = p;
    if (i0 + 0 < n && v0 == 0) { int q = atomicAdd(alone_count, 1); if (q < ALONE_CAP) alone_list[q] = i0; }
    if (i0 + 1 < n && v1 == 0) { int q = atomicAdd(alone_count, 1); if (q < ALONE_CAP) alone_list[q] = i0 + 1; }
    if (i0 + 2 < n && v2 == 0) { int q = atomicAdd(alone_count, 1); if (q < ALONE_CAP) alone_list[q] = i0 + 2; }
    if (i0 + 3 < n && v3 == 0) { int q = atomicAdd(alone_count, 1); if (q < ALONE_CAP) alone_list[q] = i0 + 3; }
}

// edges packed as uint: src | (ety << 16). Valid: N_ENTS=50000<2^16, N_RELS=200.
__global__ __launch_bounds__(256) void scatter_kernel(
    const int* __restrict__ src, const int* __restrict__ dst,
    const int* __restrict__ ety, const int* __restrict__ row_off,
    int* __restrict__ cursor, unsigned* __restrict__ edges, int e) {
    int i = blockIdx.x * 256 + threadIdx.x;
    if (i < e) {
        int v = dst[i];
        int pos = row_off[v] + atomicAdd(&cursor[v], 1);
        edges[pos] = (unsigned)src[i] | ((unsigned)ety[i] << 16);
    }
}

// ------------------------------------------------------- per-layer kernels
// S[v] = norm[v] * sum_e (h[src]+rel[et]); emitted interleaved hi/lo (Ssp).
// SPLIT=0: h is fp32 (hf). SPLIT=1: h is interleaved split (hs), reconstruct.
// TWO waves per node (block = 256 thr = 2 nodes): wave w takes half the edge
// range, half-wave per edge, 2-deep unroll -> 4 edges in flight per wave,
// 8 per node. Cross-wave combine via LDS.
template <int SPLIT>
__global__ __launch_bounds__(256) void agg_kernel(
    const float* __restrict__ hf, const unsigned* __restrict__ hs,
    const float* __restrict__ rel,
    const float* __restrict__ norm, const int* __restrict__ row_off,
    const unsigned* __restrict__ edges, unsigned* __restrict__ Ssp, int n) {
    __shared__ float part[2][128];
    int wv = threadIdx.x >> 6, lane = threadIdx.x & 63;
    int slot = wv >> 1, w = wv & 1;
    int v = blockIdx.x * 2 + slot;
    bool active = v < n;
    int s0 = 0, s1 = 0;
    if (active) { s0 = row_off[v]; s1 = row_off[v + 1]; }
    int mid = (s0 + s1 + 1) >> 1;
    int b0 = w ? mid : s0;
    int b1 = w ? s1 : mid;
    int half = lane >> 5;
    int c4 = (lane & 31) * 4;
    float4 acc = make_float4(0.f, 0.f, 0.f, 0.f);
    int e = b0;
    for (; e + 3 < b1; e += 4) {
        unsigned q0 = edges[e + half];
        unsigned q1 = edges[e + 2 + half];
        float4 h0, h1;
        if (SPLIT) {
            h0 = recon4(*(const uint4*)&hs[(size_t)(q0 & 0xFFFFu) * 128 + c4]);
            h1 = recon4(*(const uint4*)&hs[(size_t)(q1 & 0xFFFFu) * 128 + c4]);
        } else {
            h0 = *(const float4*)&hf[(size_t)(q0 & 0xFFFFu) * 128 + c4];
            h1 = *(const float4*)&hf[(size_t)(q1 & 0xFFFFu) * 128 + c4];
        }
        float4 r0 = *(const float4*)&rel[(size_t)(q0 >> 16) * 128 + c4];
        float4 r1 = *(const float4*)&rel[(size_t)(q1 >> 16) * 128 + c4];
        acc.x += (h0.x + r0.x) + (h1.x + r1.x);
        acc.y += (h0.y + r0.y) + (h1.y + r1.y);
        acc.z += (h0.z + r0.z) + (h1.z + r1.z);
        acc.w += (h0.w + r0.w) + (h1.w + r1.w);
    }
    for (; e + 1 < b1; e += 2) {
        unsigned q0 = edges[e + half];
        float4 h0 = SPLIT ? recon4(*(const uint4*)&hs[(size_t)(q0 & 0xFFFFu) * 128 + c4])
                          : *(const float4*)&hf[(size_t)(q0 & 0xFFFFu) * 128 + c4];
        float4 r0 = *(const float4*)&rel[(size_t)(q0 >> 16) * 128 + c4];
        acc.x += h0.x + r0.x; acc.y += h0.y + r0.y;
        acc.z += h0.z + r0.z; acc.w += h0.w + r0.w;
    }
    if (e < b1 && half == 0) {
        unsigned q0 = edges[e];
        float4 h0 = SPLIT ? recon4(*(const uint4*)&hs[(size_t)(q0 & 0xFFFFu) * 128 + c4])
                          : *(const float4*)&hf[(size_t)(q0 & 0xFFFFu) * 128 + c4];
        float4 r0 = *(const float4*)&rel[(size_t)(q0 >> 16) * 128 + c4];
        acc.x += h0.x + r0.x; acc.y += h0.y + r0.y;
        acc.z += h0.z + r0.z; acc.w += h0.w + r0.w;
    }
    // combine half-waves
    acc.x += __shfl_xor(acc.x, 32, 64);
    acc.y += __shfl_xor(acc.y, 32, 64);
    acc.z += __shfl_xor(acc.z, 32, 64);
    acc.w += __shfl_xor(acc.w, 32, 64);
    // combine the two waves of this node via LDS
    if (active && w == 0 && half == 0) *(float4*)&part[slot][c4] = acc;
    __syncthreads();
    if (active && w == 1 && half == 0) {
        float4 p = *(const float4*)&part[slot][c4];
        float nm = norm[v];
        uint4 o;
        o.x = packsplit((acc.x + p.x) * nm);
        o.y = packsplit((acc.y + p.y) * nm);
        o.z = packsplit((acc.z + p.z) * nm);
        o.w = packsplit((acc.w + p.w) * nm);
        *(uint4*)&Ssp[(size_t)v * 128 + c4] = o;
    }
}

// out = leaky(S@Wn + H@Wl) via bf16-split MFMA (3 products). No LDS.
// Block = 128 thr = 2 waves; wave tile 32 rows x 128 cols (each row fragment
// loaded exactly once). Grid ceil(n/64). A operands are interleaved splits.
// GEMM-1: writes Osp only (h1 split; may alias Hsp — each wave writes only
// rows it read; barrier separates). GEMM-2: writes fp32 out only.
__global__ __launch_bounds__(128) void gemm_mfma_kernel(
    const unsigned* __restrict__ Ssp, const unsigned* Hsp,
    const ushort* __restrict__ Pnh, const ushort* __restrict__ Pnl,
    const ushort* __restrict__ Plh, const ushort* __restrict__ Pll,
    float* __restrict__ out, unsigned* Osp, int n) {
    const int tid = threadIdx.x;
    const int wave = tid >> 6, lane = tid & 63;
    const int quad = lane >> 4, l16 = lane & 15;
    const int row_base = blockIdx.x * 64 + wave * 32;

    int r0c = row_base + l16;       if (r0c > n - 1) r0c = n - 1;
    int r1c = row_base + 16 + l16;  if (r1c > n - 1) r1c = n - 1;

    ffrag acc[2][8];
    #pragma unroll
    for (int rt = 0; rt < 2; ++rt)
        #pragma unroll
        for (int ct = 0; ct < 8; ++ct) acc[rt][ct] = (ffrag)0.f;

    #pragma unroll 1
    for (int half = 0; half < 2; ++half) {
        const unsigned* A = half ? Hsp : Ssp;
        const ushort* Pbh = half ? Plh : Pnh;
        const ushort* Pbl = half ? Pll : Pnl;
        #pragma unroll 1
        for (int kc = 0; kc < 4; ++kc) {
            const int koff = kc * 32 + quad * 8;
            uint4 a0a = *(const uint4*)(A + (size_t)r0c * 128 + koff);
            uint4 a0b = *(const uint4*)(A + (size_t)r0c * 128 + koff + 4);
            uint4 a1a = *(const uint4*)(A + (size_t)r1c * 128 + koff);
            uint4 a1b = *(const uint4*)(A + (size_t)r1c * 128 + koff + 4);
            bfrag ah[2], al[2];
            #pragma unroll
            for (int j = 0; j < 4; ++j) {
                unsigned u0 = ((const unsigned*)&a0a)[j];
                unsigned u1 = ((const unsigned*)&a0b)[j];
                ah[0][j]     = (short)(u0 >> 16); al[0][j]     = (short)(u0 & 0xFFFFu);
                ah[0][j + 4] = (short)(u1 >> 16); al[0][j + 4] = (short)(u1 & 0xFFFFu);
                unsigned u2 = ((const unsigned*)&a1a)[j];
                unsigned u3 = ((const unsigned*)&a1b)[j];
                ah[1][j]     = (short)(u2 >> 16); al[1][j]     = (short)(u2 & 0xFFFFu);
                ah[1][j + 4] = (short)(u3 >> 16); al[1][j + 4] = (short)(u3 & 0xFFFFu);
            }
            bfrag bh[8], bl[8];
            #pragma unroll
            for (int ct = 0; ct < 8; ++ct) {
                int bidx = ((kc * 128 + ct * 16 + l16) * 4 + quad) * 8;
                bh[ct] = *(const bfrag*)(Pbh + bidx);
                bl[ct] = *(const bfrag*)(Pbl + bidx);
            }
            #pragma unroll
            for (int rt = 0; rt < 2; ++rt)
                #pragma unroll
                for (int ct = 0; ct < 8; ++ct)
                    acc[rt][ct] = __builtin_amdgcn_mfma_f32_16x16x32_bf16(
                        ah[rt], bh[ct], acc[rt][ct], 0, 0, 0);
            #pragma unroll
            for (int rt = 0; rt < 2; ++rt)
                #pragma unroll
                for (int ct = 0; ct < 8; ++ct)
                    acc[rt][ct] = __builtin_amdgcn_mfma_f32_16x16x32_bf16(
                        ah[rt], bl[ct], acc[rt][ct], 0, 0, 0);
            #pragma unroll
            for (int rt = 0; rt < 2; ++rt)
                #pragma unroll
                for (int ct = 0; ct < 8; ++ct)
                    acc[rt][ct] = __builtin_amdgcn_mfma_f32_16x16x32_bf16(
                        al[rt], bh[ct], acc[rt][ct], 0, 0, 0);
        }
    }

    __syncthreads();  // all A reads complete before epilogue (Osp may alias Hsp)

    #pragma unroll
    for (int rt = 0; rt < 2; ++rt) {
        #pragma unroll
        for (int ct = 0; ct < 8; ++ct) {
            #pragma unroll
            for (int rg = 0; rg < 4; ++rg) {
                int r = row_base + rt * 16 + quad * 4 + rg;
                if (r < n) {
                    int c = ct * 16 + l16;
                    float v = acc[rt][ct][rg];
                    v = v >= 0.f ? v : v * SLOPE;
                    if (out) out[(size_t)r * 128 + c] = v;
                    if (Osp) Osp[(size_t)r * 128 + c] = packsplit(v);
                }
            }
        }
    }
}

// Alone nodes: o = leaky(hrow @ Wa).
// Layer 0 (by_node=1): hrow = ent[v]; writes Osp (h1 split) + asave fp32.
// Layer 1 (by_node=0): hrow = asave[i]; writes out fp32.
__global__ __launch_bounds__(128) void fixup_kernel(
    const float* __restrict__ Hrows, int by_node,
    const float* __restrict__ Wa,
    const int* __restrict__ alone_list, const int* __restrict__ alone_count,
    float* out, unsigned* Osp, float* asave) {
    int cnt = *alone_count;
    if (cnt > ALONE_CAP) cnt = ALONE_CAP;
    int t = threadIdx.x;
    for (int i = blockIdx.x; i < cnt; i += gridDim.x) {
        int v = alone_list[i];
        const float* hrow = Hrows + (size_t)(by_node ? v : i) * 128;
        float acc = 0.f;
        for (int k = 0; k < 128; ++k)
            acc += hrow[k] * Wa[k * 128 + t];
        float o = acc >= 0.f ? acc : acc * SLOPE;
        if (out) out[(size_t)v * 128 + t] = o;
        if (Osp) Osp[(size_t)v * 128 + t] = packsplit(o);
        if (asave) asave[(size_t)i * 128 + t] = o;
    }
}

extern "C" void kernel_launch(void* const* d_in, const int* in_sizes, int n_in,
                              void* d_out, int out_size, void* d_ws, size_t ws_size,
                              hipStream_t stream) {
    const float* ent  = (const float*)d_in[0];
    const float* rel  = (const float*)d_in[1];
    const float* norm = (const float*)d_in[2];
    const float* Wn   = (const float*)d_in[3];
    const float* Wl   = (const float*)d_in[4];
    const float* Wa   = (const float*)d_in[5];
    const int*   src  = (const int*)d_in[6];
    const int*   dst  = (const int*)d_in[7];
    const int*   ety  = (const int*)d_in[8];
    float* out = (float*)d_out;

    const int n = in_sizes[2];   // 50000
    const int e = in_sizes[7];   // 500000

    // workspace layout  (zeroed prefix: deg, cursor, alone_count, partial, flags)
    char* ws = (char*)d_ws;
    int* deg         = (int*)ws;          // n
    int* cursor      = deg + n;           // n
    int* alone_count = cursor + n;        // 1
    int* partial     = alone_count + 1;   // 64
    int* flags       = partial + 64;      // 64
    size_t zbytes = (size_t)(2 * n + 1 + 128) * sizeof(int);
    size_t p = (zbytes + 255) & ~(size_t)255;
    int* row_off = (int*)(ws + p);        // n+1
    p += (((size_t)(n + 1) * 4) + 255) & ~(size_t)255;
    int* alone_list = (int*)(ws + p);     // ALONE_CAP
    p += (((size_t)ALONE_CAP * 4) + 255) & ~(size_t)255;
    float* asave = (float*)(ws + p);      // ALONE_CAP*128 f32 (1 MB)
    p += (((size_t)ALONE_CAP * 128 * 4) + 255) & ~(size_t)255;
    unsigned* edges = (unsigned*)(ws + p);// e packed (2 MB)
    p += (((size_t)e * 4) + 255) & ~(size_t)255;
    unsigned* Ssp = (unsigned*)(ws + p);  // n*128 interleaved split (25.6 MB)
    p += (((size_t)n * 128 * 4) + 255) & ~(size_t)255;
    unsigned* Esp = (unsigned*)(ws + p);  // ent split; becomes h1 split (25.6 MB)
    p += (((size_t)n * 128 * 4) + 255) & ~(size_t)255;
    ushort* packW = (ushort*)(ws + p);    // 4 mats x (hi16K + lo16K) (256 KB)
    p += 4 * 32768 * 2;

    const int eb = (e + 255) / 256;             // 1954
    const int cb = (n * 32 + 255) / 256;        // 6250 (float4 units)
    const int nparts = (n + 1023) / 1024;       // 49 (<=64 required)
    const int gb = (n + 63) / 64;               // 782
    const int ab = (n + 1) / 2;                 // 25000 (2 nodes/block)

    hipMemsetAsync(ws, 0, zbytes, stream);
    prep_kernel<<<eb + cb + 32, 256, 0, stream>>>(dst, deg, e, eb,
                                                  ent, Esp, n * 32, cb,
                                                  Wn, Wl, packW);
    scan_kernel<<<nparts, 256, 0, stream>>>(deg, partial, flags, row_off,
                                            alone_list, alone_count, n);
    scatter_kernel<<<eb, 256, 0, stream>>>(src, dst, ety, row_off, cursor, edges, e);

    // layer 0: ent -> h1 split (in Esp; alias-safe: waves write only rows they read)
    agg_kernel<0><<<ab, 256, 0, stream>>>(ent, nullptr, rel, norm, row_off, edges, Ssp, n);
    gemm_mfma_kernel<<<gb, 128, 0, stream>>>(Ssp, Esp,
                                             packW, packW + 16384,
                                             packW + 32768, packW + 49152,
                                             nullptr, Esp, n);
    fixup_kernel<<<16, 128, 0, stream>>>(ent, 1, Wa, alone_list, alone_count,
                                         nullptr, Esp, asave);

    // layer 1: h1 split -> out (fp32, d_out). fixup-2 reads asave.
    agg_kernel<1><<<ab, 256, 0, stream>>>(nullptr, Esp, rel, norm, row_off, edges, Ssp, n);
    gemm_mfma_kernel<<<gb, 128, 0, stream>>>(Ssp, Esp,
                                             packW + 65536, packW + 81920,
                                             packW + 98304, packW + 114688,
                                             out, nullptr, n);
    fixup_kernel<<<16, 128, 0, stream>>>(asave, 0, Wa + 16384, alone_list, alone_count,
                                         out, nullptr, nullptr);
}